// Round 1
// baseline (212.500 us; speedup 1.0000x reference)
//
#include <hip/hip_runtime.h>

#define IN_CH 256
#define OUT_CH 8
#define TILE_NODES 32
#define LDS_STRIDE 260   // 256 + 4: keeps float4 alignment, breaks bank-conflict stride

// ---------------------------------------------------------------------------
// Projection: P1 = X @ W1^T, P2 = X @ W2^T   (X: [n,256] f32, W*: [8,256] f32)
// Block = 256 threads handles TILE_NODES=32 nodes.
// Thread t -> (node = t>>3, o = t&7); computes both dot products (512 FMA).
// ---------------------------------------------------------------------------
__global__ __launch_bounds__(256) void proj_kernel(
    const float* __restrict__ X,
    const float* __restrict__ W1,
    const float* __restrict__ W2,
    float* __restrict__ P1,
    float* __restrict__ P2,
    int n)
{
    __shared__ float Xs[TILE_NODES][LDS_STRIDE];
    __shared__ float Ws[2 * OUT_CH][LDS_STRIDE];

    const int tid  = threadIdx.x;
    const int base = blockIdx.x * TILE_NODES;

    // Stage W1 (512 float4) and W2 into LDS: 2 iters/thread each.
    {
        const float4* W1v = (const float4*)W1;
        const float4* W2v = (const float4*)W2;
        for (int i = tid; i < (OUT_CH * IN_CH) / 4; i += 256) {
            int r = (i * 4) >> 8;   // row 0..7
            int c = (i * 4) & 255;  // col, multiple of 4
            *(float4*)&Ws[r][c]          = W1v[i];
            *(float4*)&Ws[OUT_CH + r][c] = W2v[i];
        }
    }
    // Stage X tile: 32 rows x 256 cols = 2048 float4, 8 per thread, coalesced.
    {
        const float4* Xv = (const float4*)(X + (size_t)base * IN_CH);
        for (int i = tid; i < (TILE_NODES * IN_CH) / 4; i += 256) {
            int r = (i * 4) >> 8;
            int c = (i * 4) & 255;
            float4 v;
            if (base + r < n) v = Xv[i];
            else              v = make_float4(0.f, 0.f, 0.f, 0.f);
            *(float4*)&Xs[r][c] = v;
        }
    }
    __syncthreads();

    const int node = tid >> 3;
    const int o    = tid & 7;

    float acc1 = 0.f, acc2 = 0.f;
    #pragma unroll
    for (int k = 0; k < IN_CH; k += 4) {
        float4 x  = *(const float4*)&Xs[node][k];
        float4 w1 = *(const float4*)&Ws[o][k];
        float4 w2 = *(const float4*)&Ws[OUT_CH + o][k];
        acc1 += x.x * w1.x + x.y * w1.y + x.z * w1.z + x.w * w1.w;
        acc2 += x.x * w2.x + x.y * w2.y + x.z * w2.z + x.w * w2.w;
    }

    const int gnode = base + node;
    if (gnode < n) {
        // index = gnode*8 + o = base*8 + tid -> fully contiguous store per block
        P1[(size_t)base * OUT_CH + tid] = acc1;
        P2[(size_t)base * OUT_CH + tid] = acc2;
    }
}

// ---------------------------------------------------------------------------
// Gather: out[e] = P1[e0[e]] + P2[e1[e]]   (8 floats per edge = 2x float4)
// ---------------------------------------------------------------------------
__global__ __launch_bounds__(256) void gather_kernel(
    const int* __restrict__ e0,
    const int* __restrict__ e1,
    const float4* __restrict__ P1v,   // [n*2] float4
    const float4* __restrict__ P2v,
    float4* __restrict__ outv,        // [E*2] float4
    int E, int n)
{
    const int stride = gridDim.x * blockDim.x;
    const unsigned nmax = (unsigned)(n - 1);
    for (int e = blockIdx.x * blockDim.x + threadIdx.x; e < E; e += stride) {
        unsigned i0 = (unsigned)e0[e];
        unsigned i1 = (unsigned)e1[e];
        i0 = i0 > nmax ? nmax : i0;   // defensive clamp (no-op for valid input)
        i1 = i1 > nmax ? nmax : i1;
        float4 a0 = P1v[2u * i0];
        float4 a1 = P1v[2u * i0 + 1u];
        float4 b0 = P2v[2u * i1];
        float4 b1 = P2v[2u * i1 + 1u];
        float4 r0, r1;
        r0.x = a0.x + b0.x; r0.y = a0.y + b0.y; r0.z = a0.z + b0.z; r0.w = a0.w + b0.w;
        r1.x = a1.x + b1.x; r1.y = a1.y + b1.y; r1.z = a1.z + b1.z; r1.w = a1.w + b1.w;
        size_t oi = 2u * (size_t)e;
        outv[oi]     = r0;
        outv[oi + 1] = r1;
    }
}

extern "C" void kernel_launch(void* const* d_in, const int* in_sizes, int n_in,
                              void* d_out, int out_size, void* d_ws, size_t ws_size,
                              hipStream_t stream) {
    const float* X    = (const float*)d_in[0];
    const int*   eidx = (const int*)d_in[1];     // int32 per harness convention
    const float* W1   = (const float*)d_in[2];
    const float* W2   = (const float*)d_in[3];
    float*       out  = (float*)d_out;

    const int n = in_sizes[0] / IN_CH;           // 100000
    const int E = in_sizes[1] / 2;               // 6400000

    float* P1 = (float*)d_ws;                    // [n*8] f32
    float* P2 = P1 + (size_t)n * OUT_CH;         // [n*8] f32  (total 6.4 MB)

    const int proj_blocks = (n + TILE_NODES - 1) / TILE_NODES;  // 3125
    proj_kernel<<<proj_blocks, 256, 0, stream>>>(X, W1, W2, P1, P2, n);

    const int gather_blocks = 2048;              // grid-stride, ~12 edges/thread
    gather_kernel<<<gather_blocks, 256, 0, stream>>>(
        eidx, eidx + E, (const float4*)P1, (const float4*)P2,
        (float4*)out, E, n);
}